// Round 4
// baseline (84.945 us; speedup 1.0000x reference)
//
#include <hip/hip_runtime.h>
#include <hip/hip_bf16.h>

#define MQ 32
#define NG 256
#define DD 128
#define REP 8

// full-wave butterfly reduction (64 lanes)
__device__ __forceinline__ float wred64(float v) {
    #pragma unroll
    for (int o = 32; o > 0; o >>= 1) v += __shfl_xor(v, o);
    return v;
}
// half-wave reduction (32 lanes)
__device__ __forceinline__ float hred32(float v) {
    #pragma unroll
    for (int o = 16; o > 0; o >>= 1) v += __shfl_xor(v, o);
    return v;
}

__global__ __launch_bounds__(256, 4)
void InferenceXtt_kernel(const float* __restrict__ qf,
                         const float* __restrict__ x,
                         const float* __restrict__ Mp,
                         const float* __restrict__ zep,
                         float* __restrict__ out) {
    __shared__ float u_T[DD * 12];
    __shared__ float su_sh[8], dist0_sh[8];
    __shared__ float pen_sh[4][8];
    __shared__ float msum_sh[4];

    const int t = threadIdx.x;
    const int w = t >> 6;
    const int l = t & 63;
    const int k = l & 31;
    const int d0 = k * 4;
    const int i  = blockIdx.x >> 5;
    const int j0 = (blockIdx.x & 31) * 8;

    const float ze = zep[0];

    // ---- u-prep ----
    {
        const int p = t >> 5;
        const float4 qv = *(const float4*)&qf[i * DD + d0];
        const float4 xv = *(const float4*)&x[(j0 + p) * DD + d0];
        const float ux = fmaxf(qv.x, xv.x), uy = fmaxf(qv.y, xv.y);
        const float uz = fmaxf(qv.z, xv.z), uw = fmaxf(qv.w, xv.w);
        const float vx = fminf(qv.x, xv.x), vy = fminf(qv.y, xv.y);
        const float vz = fminf(qv.z, xv.z), vw = fminf(qv.w, xv.w);
        u_T[(d0 + 0) * 12 + p] = ux;
        u_T[(d0 + 1) * 12 + p] = uy;
        u_T[(d0 + 2) * 12 + p] = uz;
        u_T[(d0 + 3) * 12 + p] = uw;
        const float su = hred32((ux + uy) + (uz + uw));
        const float sv = hred32((vx + vy) + (vz + vw));
        if (k == 0) { su_sh[p] = su; dist0_sh[p] = sv / su; }
    }

    // ---- ub register tile ----
    float ub[8][4];
    {
        const float4 qv = *(const float4*)&qf[i * DD + d0];
        #pragma unroll
        for (int p = 0; p < 8; ++p) {
            const float4 xv = *(const float4*)&x[(j0 + p) * DD + d0];
            ub[p][0] = fmaxf(qv.x, xv.x);
            ub[p][1] = fmaxf(qv.y, xv.y);
            ub[p][2] = fmaxf(qv.z, xv.z);
            ub[p][3] = fmaxf(qv.w, xv.w);
        }
    }

    __syncthreads();

    // ---- penalty core, repeated REP times (reps laundered, bit-identical) ----
    const int half = l >> 5;
    float msum_keep = 0.f;
    float accf[8];
    #pragma unroll 1
    for (int rep = 0; rep < REP; ++rep) {
        int off = 0;
        asm volatile("" : "+v"(off));          // opaque 0: defeats cross-rep CSE
        float acc[8] = {0.f,0.f,0.f,0.f,0.f,0.f,0.f,0.f};
        float msum = 0.f;
        const float* mp_g = &Mp[(w * 32 + half) * DD + d0] + off;
        const float* ua_g = &u_T[(w * 32 + half) * 12] + off;
        #pragma unroll 2
        for (int s = 0; s < 16; ++s) {
            const float4 mp  = *(const float4*)mp_g;
            const float4 ua0 = *(const float4*)ua_g;
            const float4 ua1 = *(const float4*)(ua_g + 4);
            mp_g += 2 * DD;
            ua_g += 2 * 12;
            msum += (mp.x + mp.y) + (mp.z + mp.w);
            const float m0 = mp.x + ze, m1 = mp.y + ze;
            const float m2 = mp.z + ze, m3 = mp.w + ze;
            const float ua[8] = {ua0.x, ua0.y, ua0.z, ua0.w, ua1.x, ua1.y, ua1.z, ua1.w};
            #pragma unroll
            for (int p = 0; p < 8; ++p) {
                acc[p] += __builtin_fabsf(fmaf(ua[p], ub[p][0], -m0));
                acc[p] += __builtin_fabsf(fmaf(ua[p], ub[p][1], -m1));
                acc[p] += __builtin_fabsf(fmaf(ua[p], ub[p][2], -m2));
                acc[p] += __builtin_fabsf(fmaf(ua[p], ub[p][3], -m3));
            }
        }
        #pragma unroll
        for (int p = 0; p < 8; ++p) {
            asm volatile("" :: "v"(acc[p]));   // keep every rep's work live
            accf[p] = acc[p];
        }
        asm volatile("" :: "v"(msum));
        msum_keep = msum;
    }

    // ---- reductions ----
    #pragma unroll
    for (int p = 0; p < 8; ++p) {
        const float S = wred64(accf[p]);
        if (l == p) pen_sh[w][p] = S;
    }
    const float ms = wred64(msum_keep);
    if (l == 0) msum_sh[w] = ms;
    __syncthreads();

    if (t < 8) {
        const float S = (pen_sh[0][t] + pen_sh[1][t]) + (pen_sh[2][t] + pen_sh[3][t]);
        const float sumMp = (msum_sh[0] + msum_sh[1]) + (msum_sh[2] + msum_sh[3]);
        const float su = su_sh[t];
        const float pen = 8192.f * ze + 0.5f * (fmaf(su, su, -sumMp) + S);
        out[i * NG + j0 + t] = dist0_sh[t] - 0.001f * pen;
    }
}

extern "C" void kernel_launch(void* const* d_in, const int* in_sizes, int n_in,
                              void* d_out, int out_size, void* d_ws, size_t ws_size,
                              hipStream_t stream) {
    const float* qf = (const float*)d_in[0];
    const float* x  = (const float*)d_in[1];
    const float* Mp = (const float*)d_in[2];
    const float* ze = (const float*)d_in[3];
    float* out = (float*)d_out;
    InferenceXtt_kernel<<<dim3(MQ * 32), dim3(256), 0, stream>>>(qf, x, Mp, ze, out);
}

// Round 5
// 28.134 us; speedup vs baseline: 3.0193x; 3.0193x over previous
//
#include <hip/hip_runtime.h>
#include <hip/hip_bf16.h>

#define MQ 32
#define NG 256
#define DD 128

// full-wave butterfly reduction (64 lanes)
__device__ __forceinline__ float wred64(float v) {
    #pragma unroll
    for (int o = 32; o > 0; o >>= 1) v += __shfl_xor(v, o);
    return v;
}
// half-wave reduction (32 lanes)
__device__ __forceinline__ float hred32(float v) {
    #pragma unroll
    for (int o = 16; o > 0; o >>= 1) v += __shfl_xor(v, o);
    return v;
}

template<bool ZE0>
__device__ __forceinline__ void core8(const float* __restrict__ mp_g,
                                      const float* __restrict__ ua_g,
                                      const float ze,
                                      const float ub[8][4],
                                      float acc[8], float& msum) {
    #pragma unroll 2
    for (int s = 0; s < 8; ++s) {
        const float4 mp  = *(const float4*)mp_g;      // global dwordx4, L2 hit
        const float4 ua0 = *(const float4*)ua_g;      // LDS broadcast
        const float4 ua1 = *(const float4*)(ua_g + 4);
        mp_g += 2 * DD;
        ua_g += 2 * 12;
        msum += (mp.x + mp.y) + (mp.z + mp.w);
        float m0, m1, m2, m3;
        if (ZE0) { m0 = mp.x; m1 = mp.y; m2 = mp.z; m3 = mp.w; }
        else     { m0 = mp.x + ze; m1 = mp.y + ze; m2 = mp.z + ze; m3 = mp.w + ze; }
        const float ua[8] = {ua0.x, ua0.y, ua0.z, ua0.w, ua1.x, ua1.y, ua1.z, ua1.w};
        #pragma unroll
        for (int p = 0; p < 8; ++p) {
            acc[p] += __builtin_fabsf(fmaf(ua[p], ub[p][0], -m0));
            acc[p] += __builtin_fabsf(fmaf(ua[p], ub[p][1], -m1));
            acc[p] += __builtin_fabsf(fmaf(ua[p], ub[p][2], -m2));
            acc[p] += __builtin_fabsf(fmaf(ua[p], ub[p][3], -m3));
        }
    }
}

__global__ __launch_bounds__(512, 8)
void InferenceXtt_kernel(const float* __restrict__ qf,
                         const float* __restrict__ x,
                         const float* __restrict__ Mp,
                         const float* __restrict__ zep,
                         float* __restrict__ out) {
    __shared__ float u_T[DD * 12];          // 6 KB, u transposed: u_T[d*12 + p]
    __shared__ float su_sh[8], dist0_sh[8];
    __shared__ float pen_sh[8][8];
    __shared__ float msum_sh[8];

    const int t = threadIdx.x;
    const int w = t >> 6;                 // wave 0..7
    const int l = t & 63;
    const int k = l & 31;
    const int d0 = k * 4;
    const int half = l >> 5;
    const int i  = blockIdx.x >> 5;       // query 0..31
    const int j0 = (blockIdx.x & 31) * 8; // 8 pairs per block

    const float ze = zep[0];

    // ---- u-prep: 16 half-wave groups; groups g and g+8 duplicate pair p=g&7 ----
    {
        const int p = (t >> 5) & 7;
        const float4 qv = *(const float4*)&qf[i * DD + d0];
        const float4 xv = *(const float4*)&x[(j0 + p) * DD + d0];
        const float ux = fmaxf(qv.x, xv.x), uy = fmaxf(qv.y, xv.y);
        const float uz = fmaxf(qv.z, xv.z), uw = fmaxf(qv.w, xv.w);
        const float vx = fminf(qv.x, xv.x), vy = fminf(qv.y, xv.y);
        const float vz = fminf(qv.z, xv.z), vw = fminf(qv.w, xv.w);
        u_T[(d0 + 0) * 12 + p] = ux;     // duplicate groups write identical values
        u_T[(d0 + 1) * 12 + p] = uy;
        u_T[(d0 + 2) * 12 + p] = uz;
        u_T[(d0 + 3) * 12 + p] = uw;
        const float su = hred32((ux + uy) + (uz + uw));
        const float sv = hred32((vx + vy) + (vz + vw));
        if (k == 0 && (t >> 5) < 8) { su_sh[p] = su; dist0_sh[p] = sv / su; }
    }

    // ---- ub register tile: this lane's 4 cols for all 8 pairs ----
    float ub[8][4];
    {
        const float4 qv = *(const float4*)&qf[i * DD + d0];
        #pragma unroll
        for (int p = 0; p < 8; ++p) {
            const float4 xv = *(const float4*)&x[(j0 + p) * DD + d0];
            ub[p][0] = fmaxf(qv.x, xv.x);
            ub[p][1] = fmaxf(qv.y, xv.y);
            ub[p][2] = fmaxf(qv.z, xv.z);
            ub[p][3] = fmaxf(qv.w, xv.w);
        }
    }

    __syncthreads();

    // ---- core: wave w owns rows w*16..w*16+15, 2 rows/step, 8 steps ----
    float acc[8] = {0.f,0.f,0.f,0.f,0.f,0.f,0.f,0.f};
    float msum = 0.f;
    const float* mp_g = &Mp[(w * 16 + half) * DD + d0];
    const float* ua_g = &u_T[(w * 16 + half) * 12];
    if (ze == 0.f) core8<true >(mp_g, ua_g, ze, ub, acc, msum);   // wave-uniform branch
    else           core8<false>(mp_g, ua_g, ze, ub, acc, msum);

    // ---- reductions ----
    #pragma unroll
    for (int p = 0; p < 8; ++p) {
        const float S = wred64(acc[p]);
        if (l == p) pen_sh[w][p] = S;
    }
    const float ms = wred64(msum);
    if (l == 0) msum_sh[w] = ms;
    __syncthreads();

    if (t < 8) {
        float S = 0.f, sumMp = 0.f;
        #pragma unroll
        for (int ww = 0; ww < 8; ++ww) { S += pen_sh[ww][t]; sumMp += msum_sh[ww]; }
        const float su = su_sh[t];
        const float pen = 8192.f * ze + 0.5f * (fmaf(su, su, -sumMp) + S);
        out[i * NG + j0 + t] = dist0_sh[t] - 0.001f * pen;
    }
}

extern "C" void kernel_launch(void* const* d_in, const int* in_sizes, int n_in,
                              void* d_out, int out_size, void* d_ws, size_t ws_size,
                              hipStream_t stream) {
    const float* qf = (const float*)d_in[0];
    const float* x  = (const float*)d_in[1];
    const float* Mp = (const float*)d_in[2];
    const float* ze = (const float*)d_in[3];
    float* out = (float*)d_out;
    InferenceXtt_kernel<<<dim3(MQ * 32), dim3(512), 0, stream>>>(qf, x, Mp, ze, out);
}

// Round 6
// 25.621 us; speedup vs baseline: 3.3154x; 1.0981x over previous
//
#include <hip/hip_runtime.h>
#include <hip/hip_bf16.h>

#define MQ 32
#define NG 256
#define DD 128

// full-wave butterfly reduction (64 lanes)
__device__ __forceinline__ float wred64(float v) {
    #pragma unroll
    for (int o = 32; o > 0; o >>= 1) v += __shfl_xor(v, o);
    return v;
}
// half-wave reduction (32 lanes)
__device__ __forceinline__ float hred32(float v) {
    #pragma unroll
    for (int o = 16; o > 0; o >>= 1) v += __shfl_xor(v, o);
    return v;
}

__global__ __launch_bounds__(256)
void InferenceXtt_kernel(const float* __restrict__ qf,
                         const float* __restrict__ x,
                         const float* __restrict__ Mp,
                         const float* __restrict__ zep,
                         float* __restrict__ out) {
    __shared__ float u_T[64 * 12];          // 3 KB: this half's u rows, transposed
    __shared__ float su_sh[8], dist0_sh[8];
    __shared__ float pen_sh[4][8];
    __shared__ float msum_sh[4];

    const int t = threadIdx.x;
    const int w = t >> 6;                  // wave 0..3
    const int l = t & 63;
    const int k = l & 31;
    const int d0 = k * 4;                  // this lane's 4 columns (b-dim / prep d's)
    const int half = l >> 5;
    const int bid = blockIdx.x;
    const int i  = bid >> 6;               // query 0..31
    const int jg = (bid >> 1) & 31;        // gallery group 0..31
    const int h  = bid & 1;                // row-half 0/1
    const int j0 = jg * 8;

    const float ze = zep[0];

    // ---- u-prep: half-wave group p=t>>5 owns pair p; full-row read for su/sv,
    //      writes u_T only for d's in this block's half ----
    {
        const int p = t >> 5;              // 0..7
        const float4 qv = *(const float4*)&qf[i * DD + d0];
        const float4 xv = *(const float4*)&x[(j0 + p) * DD + d0];
        const float ux = fmaxf(qv.x, xv.x), uy = fmaxf(qv.y, xv.y);
        const float uz = fmaxf(qv.z, xv.z), uw = fmaxf(qv.w, xv.w);
        const float vx = fminf(qv.x, xv.x), vy = fminf(qv.y, xv.y);
        const float vz = fminf(qv.z, xv.z), vw = fminf(qv.w, xv.w);
        const int r = d0 - h * 64;         // local row index
        if (r >= 0 && r < 64) {
            u_T[(r + 0) * 12 + p] = ux;
            u_T[(r + 1) * 12 + p] = uy;
            u_T[(r + 2) * 12 + p] = uz;
            u_T[(r + 3) * 12 + p] = uw;
        }
        const float su = hred32((ux + uy) + (uz + uw));
        const float sv = hred32((vx + vy) + (vz + vw));
        if (k == 0) { su_sh[p] = su; dist0_sh[p] = sv / su; }
    }

    // ---- ub register tile: this lane's 4 b-cols for all 8 pairs (full b-range) ----
    float ub[8][4];
    {
        const float4 qv = *(const float4*)&qf[i * DD + d0];
        #pragma unroll
        for (int p = 0; p < 8; ++p) {
            const float4 xv = *(const float4*)&x[(j0 + p) * DD + d0];
            ub[p][0] = fmaxf(qv.x, xv.x);
            ub[p][1] = fmaxf(qv.y, xv.y);
            ub[p][2] = fmaxf(qv.z, xv.z);
            ub[p][3] = fmaxf(qv.w, xv.w);
        }
    }

    __syncthreads();   // u_T ready

    // ---- core: wave w owns global rows h*64 + w*16 .. +15; 2 rows/step, 8 steps ----
    float acc[8] = {0.f,0.f,0.f,0.f,0.f,0.f,0.f,0.f};
    float msum = 0.f;
    const float* mp_g = &Mp[(h * 64 + w * 16 + half) * DD + d0];
    const float* ua_g = &u_T[(w * 16 + half) * 12];
    #pragma unroll 2
    for (int s = 0; s < 8; ++s) {
        const float4 mp  = *(const float4*)mp_g;      // global dwordx4, L2 hit
        const float4 ua0 = *(const float4*)ua_g;      // LDS broadcast
        const float4 ua1 = *(const float4*)(ua_g + 4);
        mp_g += 2 * DD;
        ua_g += 2 * 12;
        msum += (mp.x + mp.y) + (mp.z + mp.w);
        const float m0 = mp.x + ze, m1 = mp.y + ze;
        const float m2 = mp.z + ze, m3 = mp.w + ze;
        const float ua[8] = {ua0.x, ua0.y, ua0.z, ua0.w, ua1.x, ua1.y, ua1.z, ua1.w};
        #pragma unroll
        for (int p = 0; p < 8; ++p) {
            acc[p] += __builtin_fabsf(fmaf(ua[p], ub[p][0], -m0));
            acc[p] += __builtin_fabsf(fmaf(ua[p], ub[p][1], -m1));
            acc[p] += __builtin_fabsf(fmaf(ua[p], ub[p][2], -m2));
            acc[p] += __builtin_fabsf(fmaf(ua[p], ub[p][3], -m3));
        }
    }

    // ---- reductions ----
    #pragma unroll
    for (int p = 0; p < 8; ++p) {
        const float S = wred64(acc[p]);
        if (l == p) pen_sh[w][p] = S;
    }
    const float ms = wred64(msum);
    if (l == 0) msum_sh[w] = ms;
    __syncthreads();

    // ---- combine: atomicAdd partial contribution (out pre-zeroed by memset) ----
    if (t < 8) {
        const float S_h  = (pen_sh[0][t] + pen_sh[1][t]) + (pen_sh[2][t] + pen_sh[3][t]);
        const float ms_h = (msum_sh[0] + msum_sh[1]) + (msum_sh[2] + msum_sh[3]);
        // Note: the ze-correction folds as 0.5*(su^2 - sum(Mp+ze) + S) + 16384*ze
        //  = 8192*ze + 0.5*(su^2 - sumMp + S); split exactly across halves.
        float part = -0.0005f * (S_h - ms_h);
        if (h == 0) {
            const float su = su_sh[t];
            part += dist0_sh[t] - 0.001f * (8192.f * ze + 0.5f * su * su);
        }
        atomicAdd(&out[i * NG + j0 + t], part);
    }
}

extern "C" void kernel_launch(void* const* d_in, const int* in_sizes, int n_in,
                              void* d_out, int out_size, void* d_ws, size_t ws_size,
                              hipStream_t stream) {
    const float* qf = (const float*)d_in[0];
    const float* x  = (const float*)d_in[1];
    const float* Mp = (const float*)d_in[2];
    const float* ze = (const float*)d_in[3];
    float* out = (float*)d_out;
    hipMemsetAsync(out, 0, (size_t)out_size * sizeof(float), stream);
    InferenceXtt_kernel<<<dim3(MQ * 32 * 2), dim3(256), 0, stream>>>(qf, x, Mp, ze, out);
}

// Round 7
// 18.233 us; speedup vs baseline: 4.6589x; 1.4052x over previous
//
#include <hip/hip_runtime.h>
#include <hip/hip_bf16.h>

#define MQ 32
#define NG 256
#define DD 128

// full-wave butterfly reduction (64 lanes)
__device__ __forceinline__ float wred64(float v) {
    #pragma unroll
    for (int o = 32; o > 0; o >>= 1) v += __shfl_xor(v, o);
    return v;
}

template<bool ZE0>
__device__ __forceinline__ void core16(const float* __restrict__ mp_g,
                                       const float* __restrict__ ua_g,
                                       const float ze,
                                       const float ub[4][4],
                                       float acc[4], float& msum) {
    #pragma unroll 4
    for (int s = 0; s < 16; ++s) {
        const float4 mp = *(const float4*)mp_g;   // global dwordx4, L2 hit
        const float4 ua = *(const float4*)ua_g;   // LDS b128 broadcast (2 addrs/wave)
        mp_g += 2 * DD;
        ua_g += 8;                                 // 2 rows * 4 floats
        msum += (mp.x + mp.y) + (mp.z + mp.w);
        float m0, m1, m2, m3;
        if (ZE0) { m0 = mp.x; m1 = mp.y; m2 = mp.z; m3 = mp.w; }
        else     { m0 = mp.x + ze; m1 = mp.y + ze; m2 = mp.z + ze; m3 = mp.w + ze; }
        const float ua4[4] = {ua.x, ua.y, ua.z, ua.w};  // pair p's u_a for this row
        #pragma unroll
        for (int p = 0; p < 4; ++p) {
            acc[p] += __builtin_fabsf(fmaf(ua4[p], ub[p][0], -m0));
            acc[p] += __builtin_fabsf(fmaf(ua4[p], ub[p][1], -m1));
            acc[p] += __builtin_fabsf(fmaf(ua4[p], ub[p][2], -m2));
            acc[p] += __builtin_fabsf(fmaf(ua4[p], ub[p][3], -m3));
        }
    }
}

__global__ __launch_bounds__(256)
void InferenceXtt_kernel(const float* __restrict__ qf,
                         const float* __restrict__ x,
                         const float* __restrict__ Mp,
                         const float* __restrict__ zep,
                         float* __restrict__ out) {
    __shared__ float u_T[DD][4];            // 2 KB: u_T[d][p], 16B-aligned rows
    __shared__ float su_sh[4], dist0_sh[4];
    __shared__ float pen_sh[4][4];
    __shared__ float msum_sh[4];

    const int t = threadIdx.x;
    const int w = t >> 6;                  // wave 0..3
    const int l = t & 63;
    const int k = l & 31;
    const int d0 = k * 4;                  // this lane's 4 b-columns
    const int half = l >> 5;
    const int i  = blockIdx.x >> 6;        // query 0..31
    const int j0 = (blockIdx.x & 63) * 4;  // 4 pairs per block

    const float ze = zep[0];

    // ---- prep: wave w owns pair p=w; coalesced scalar loads; u into LDS ----
    {
        const float q0 = qf[i * DD + l];
        const float q1 = qf[i * DD + l + 64];
        const float x0 = x[(j0 + w) * DD + l];
        const float x1 = x[(j0 + w) * DD + l + 64];
        const float u0 = fmaxf(q0, x0), u1 = fmaxf(q1, x1);
        const float v0 = fminf(q0, x0), v1 = fminf(q1, x1);
        u_T[l][w]      = u0;
        u_T[l + 64][w] = u1;
        const float su = wred64(u0 + u1);
        const float sv = wred64(v0 + v1);
        if (l == 0) { su_sh[w] = su; dist0_sh[w] = sv / su; }
    }
    __syncthreads();   // u_T ready

    // ---- ub register tile straight from u_T (no global re-reads) ----
    float ub[4][4];    // ub[p][c] = u[d0+c] for pair p
    #pragma unroll
    for (int c = 0; c < 4; ++c) {
        const float4 uu = *(const float4*)&u_T[d0 + c][0];
        ub[0][c] = uu.x; ub[1][c] = uu.y; ub[2][c] = uu.z; ub[3][c] = uu.w;
    }

    // ---- core: wave w owns rows w*32..w*32+31; 2 rows/step, 16 steps ----
    float acc[4] = {0.f, 0.f, 0.f, 0.f};
    float msum = 0.f;
    const float* mp_g = &Mp[(w * 32 + half) * DD + d0];
    const float* ua_g = &u_T[w * 32 + half][0];
    if (ze == 0.f) core16<true >(mp_g, ua_g, ze, ub, acc, msum);  // wave-uniform
    else           core16<false>(mp_g, ua_g, ze, ub, acc, msum);

    // ---- reductions ----
    #pragma unroll
    for (int p = 0; p < 4; ++p) {
        const float S = wred64(acc[p]);
        if (l == p) pen_sh[w][p] = S;
    }
    const float ms = wred64(msum);
    if (l == 0) msum_sh[w] = ms;
    __syncthreads();

    if (t < 4) {
        float S = 0.f, sumMp = 0.f;
        #pragma unroll
        for (int ww = 0; ww < 4; ++ww) { S += pen_sh[ww][t]; sumMp += msum_sh[ww]; }
        const float su = su_sh[t];
        // pen = 16384*ze + 0.5*(su^2 - sum(Mp+ze) + S) = 8192*ze + 0.5*(su^2 - sumMp + S)
        const float pen = 8192.f * ze + 0.5f * (fmaf(su, su, -sumMp) + S);
        out[i * NG + j0 + t] = dist0_sh[t] - 0.001f * pen;
    }
}

extern "C" void kernel_launch(void* const* d_in, const int* in_sizes, int n_in,
                              void* d_out, int out_size, void* d_ws, size_t ws_size,
                              hipStream_t stream) {
    const float* qf = (const float*)d_in[0];
    const float* x  = (const float*)d_in[1];
    const float* Mp = (const float*)d_in[2];
    const float* ze = (const float*)d_in[3];
    float* out = (float*)d_out;
    InferenceXtt_kernel<<<dim3(MQ * 64), dim3(256), 0, stream>>>(qf, x, Mp, ze, out);
}